// Round 17
// baseline (279.185 us; speedup 1.0000x reference)
//
#include <hip/hip_runtime.h>

// ---------------------------------------------------------------------------
// StressGNN: 2-layer GCN, 100k nodes / 1.6M edges, fp32.
//   *** r33 = ATTRIBUTION PROBE #2 ***: pipeline identical to r32 (156.3us),
//   but agg64 (idempotent) launched 6x. agg64 = (dTotal - 5*gap)/5, gap~1.5
//   (r30). Probe reverted next round; decision rule in round notes.
//   ---
//   (Â X) W = Â (X W): aggregate in the small dim (8, then 64).
//   norm factored out; h1s fp8 e4m3 rows (64B); xs bf16 (16B, L2-resident);
//   ah bf16x2 (r17). CSR: fixed-capacity buckets (r15).
//   r18 LESSON: edge-parallel scattered 4B stores -> 17x cross-XCD write amp.
//   r19 LESSON: 1.6M device-scope atomicAdds cost ~30-100us.
//   r20 LESSON: +50% bucketed payload -> +10us.
//   r21 LESSON: scatterA NOT grid/cursor-atomic-bound.
//   r22 WIN (205->196): buildB LDS-staged segment, 256-node buckets.
//   r23 small win: wide 16B gathers. r24 small win: LDS sort + coalesced out.
//   r25 LESSON (286us!): device-scope __threadfence per block serializes the
//     memory system. Finish stays a separate dispatch.
//   r26 LESSON: packed-bf16 FMA gemm2 is VALU-bound (unpack cost).
//   r27 WIN (198->168): gemm2 on v_mfma_f32_32x32x16_bf16.
//   r28 LESSON: direct-global A-fragments uncoalesced; A stays through-LDS.
//   r29 WIN (168->162.7): scatterA/buildB at 512 threads.
//   r30 PROBE: gap <= 1-2us; finish was ~6us -> r31a/r32 fixed (~1us now).
//   r31 LESSON: two-pass agg64 +18us -- smaller SHARED footprint doesn't fix
//     L2 thrash (needs XCD-partitioned data). Single-pass is the structure.
//   r32 WIN (162.7->156.3): gemm2 applies Wfc + reduces to 1 float/block.
//   r15 lesson: gemm2 grid ~1024; G2_GRID=1042 balances 3125 tiles.
//   r13 lesson: do NOT fuse the gather into the GEMM kernel (occupancy).
//   Assumes n <= 131072 (src fits 17 bits, dst_local fits 8 bits, <=512 bkts).
// ---------------------------------------------------------------------------

#define CHUNK 4096
#define NB_SHIFT 8   // 256 nodes per bucket
#define BCAP 5120    // mean 4096, sigma~64 -> 16-sigma margin
#define G2_GRID 1042

typedef float v2f __attribute__((ext_vector_type(2)));
typedef __bf16 bf16x8 __attribute__((ext_vector_type(8)));
typedef float f32x16 __attribute__((ext_vector_type(16)));

__device__ __forceinline__ unsigned short f2bf(float f) {
    unsigned u = __float_as_uint(f);
    return (unsigned short)((u + 0x7fffu + ((u >> 16) & 1u)) >> 16);
}
__device__ __forceinline__ unsigned pkbf(float a, float b) {
    return ((unsigned)f2bf(b) << 16) | f2bf(a);
}
__device__ __forceinline__ float bflo(unsigned u) { return __uint_as_float(u << 16); }
__device__ __forceinline__ float bfhi(unsigned u) { return __uint_as_float(u & 0xffff0000u); }
__device__ __forceinline__ bf16x8 asbf8(uint4 v) { return __builtin_bit_cast(bf16x8, v); }

// r24 sort + r25b pk-in-LDS + r29: 512 threads (halved phase trip counts).
__global__ __launch_bounds__(512) void scatterA(const int* __restrict__ ei, int E,
                                                int* __restrict__ cursor,
                                                unsigned int* __restrict__ bucketed) {
    __shared__ unsigned int pk[CHUNK];     // 16KB packed edges (chunk order)
    __shared__ unsigned short bk[CHUNK];   // 8KB  bucket id per edge
    __shared__ unsigned int spk[CHUNK];    // 16KB bucket-sorted packed edges
    __shared__ unsigned short sbk[CHUNK];  // 8KB  bucket id per sorted slot
    __shared__ int h[512], hsc[512], lcur[512], rbase[512];  // 8KB
    int tid = threadIdx.x;
    h[tid] = 0;
    lcur[tid] = 0;
    __syncthreads();
    int cbase = blockIdx.x * CHUNK;
    int cN = min(CHUNK, E - cbase);
    const int* src = ei;
    const int* dst = ei + E;
    // phase 1: read edges once; pack into LDS; histogram buckets
    for (int i = tid; i < cN; i += 512) {
        int s = src[cbase + i], d = dst[cbase + i];
        int b = d >> NB_SHIFT;
        pk[i] = (unsigned)s | ((unsigned)(d & 255) << 17);
        bk[i] = (unsigned short)b;
        atomicAdd(&h[b], 1);
    }
    __syncthreads();
    // inclusive Hillis-Steele scan over 512 (one element per thread)
    hsc[tid] = h[tid];
    __syncthreads();
    for (int off = 1; off < 512; off <<= 1) {
        int v0 = (tid >= off) ? hsc[tid - off] : 0;
        __syncthreads();
        hsc[tid] += v0;
        __syncthreads();
    }
    hsc[tid] -= h[tid];  // exclusive (own slot only)
    // global reservation per touched bucket
    if (h[tid]) rbase[tid] = tid * BCAP + atomicAdd(&cursor[tid], h[tid]);
    __syncthreads();
    // phase 2: LDS -> LDS bucket sort
    for (int i = tid; i < cN; i += 512) {
        int b = bk[i];
        int pos = hsc[b] + atomicAdd(&lcur[b], 1);
        spk[pos] = pk[i];
        sbk[pos] = (unsigned short)b;
    }
    __syncthreads();
    // phase 3: coalesced write-out (consecutive lanes -> consecutive addrs)
    for (int p = tid; p < cN; p += 512) {
        int b = sbk[p];
        bucketed[rbase[b] + (p - hsc[b])] = spk[p];
    }
}

// Pass B: one block per 256-node bucket, 512 threads (r29). Segment staged
// in LDS; scan; per-node scatter to LDS scsr (r24); csr_src written
// coalesced. Also writes dinv and the bf16 pre-scaled xsb rows.
__global__ __launch_bounds__(512) void buildB(
    const unsigned int* __restrict__ bucketed, const int* __restrict__ cursor,
    int* __restrict__ row_start, int* __restrict__ cntg, float* __restrict__ dinv,
    int* __restrict__ csr_src, const float* __restrict__ x,
    unsigned int* __restrict__ xsb, int n) {
    __shared__ unsigned int spk[BCAP];  // 20KB staged segment
    __shared__ int scsr[BCAP];          // 20KB sorted local csr
    __shared__ int cnt[256], sc[256], cur[256];
    __shared__ float sdinv[256];
    int tid = threadIdx.x;
    int b = blockIdx.x;
    int s0 = b * BCAP;
    int m = cursor[b];
    if (tid < 256) cnt[tid] = 0;
    __syncthreads();
    for (int e = tid; e < m; e += 512) {
        unsigned v = bucketed[s0 + e];
        spk[e] = v;
        atomicAdd(&cnt[v >> 17], 1);
    }
    __syncthreads();
    if (tid < 256) sc[tid] = cnt[tid];
    __syncthreads();
    for (int off = 1; off < 256; off <<= 1) {  // inclusive Hillis-Steele over 256
        int v0 = (tid < 256 && tid >= off) ? sc[tid - off] : 0;
        __syncthreads();
        if (tid < 256) sc[tid] += v0;
        __syncthreads();
    }
    int nb0 = b << NB_SHIFT;
    if (tid < 256) {
        int node = nb0 + tid;
        int ex = sc[tid] - cnt[tid];  // exclusive (segment-local)
        cur[tid] = ex;
        float dv = rsqrtf((float)cnt[tid] + 1.0f);
        sdinv[tid] = dv;
        if (node < n) {
            row_start[node] = s0 + ex;
            cntg[node] = cnt[tid];
            dinv[node] = dv;
        }
    }
    __syncthreads();
    // per-node sort into LDS (banked, cheap), then coalesced global write
    for (int e = tid; e < m; e += 512) {
        unsigned v = spk[e];
        int r = atomicAdd(&cur[v >> 17], 1);
        scsr[r] = (int)(v & 0x1FFFFu);
    }
    __syncthreads();
    for (int e = tid; e < m; e += 512) csr_src[s0 + e] = scsr[e];
    // xsb for this bucket's nodes: xsb[(nb0+(i>>2))*4 + (i&3)] == xsb[nb0*4+i]
    int lim = min(n - nb0, 256) * 4;
    for (int i = tid; i < lim; i += 512) {
        float2 v = ((const float2*)x)[nb0 * 4 + i];
        float dvv = sdinv[i >> 2];
        xsb[nb0 * 4 + i] = pkbf(v.x * dvv, v.y * dvv);
    }
}

// fused: ax = dinv[d]*(sum xs[src] + xs[d]);  h1q = fp8(dinv[d]*relu(ax@W1+b1)).
// Phase A (r23): node per 4-LANE GROUP; each lane = one edge SLOT loading the
// full 16B xs row (uint4), 2-deep; slot partials merged by shfl_xor butterfly.
// Phase B: per-wave 8->64 GEMM from LDS ax (broadcast reads) + fp8 store.
__global__ __launch_bounds__(256) void aggX_gemm1(
    const unsigned int* __restrict__ xsb, const float* __restrict__ dinv,
    const int* __restrict__ row_start, const int* __restrict__ cnt,
    const int* __restrict__ csr_src, const float* __restrict__ W1,
    const float* __restrict__ b1, unsigned int* __restrict__ h1q, int n) {
    __shared__ float w[512 + 64];
    __shared__ float axl[64 * 8];  // ax for this block's 64 nodes
    __shared__ float sdi[64];
    int tid = threadIdx.x;
    for (int i = tid; i < 512; i += 256) w[i] = W1[i];
    if (tid < 64) w[512 + tid] = b1[tid];
    // ---- phase A: wide gather ----
    int g = tid >> 2, l = tid & 3;
    int node = blockIdx.x * 64 + g;
    float a[8] = {};
    float di = 0.f;
    if (node < n) {
        di = dinv[node];
        const uint4* xs4 = (const uint4*)xsb;
        int e0 = row_start[node], e1 = e0 + cnt[node];
        int e = e0 + l;
        for (; e + 4 < e1; e += 8) {  // 2-deep: 2 x 16B rows in flight per lane
            int sA = csr_src[e], sB = csr_src[e + 4];
            uint4 uA = xs4[sA], uB = xs4[sB];
            a[0] += bflo(uA.x) + bflo(uB.x);
            a[1] += bfhi(uA.x) + bfhi(uB.x);
            a[2] += bflo(uA.y) + bflo(uB.y);
            a[3] += bfhi(uA.y) + bfhi(uB.y);
            a[4] += bflo(uA.z) + bflo(uB.z);
            a[5] += bfhi(uA.z) + bfhi(uB.z);
            a[6] += bflo(uA.w) + bflo(uB.w);
            a[7] += bfhi(uA.w) + bfhi(uB.w);
        }
        for (; e < e1; e += 4) {
            uint4 u = xs4[csr_src[e]];
            a[0] += bflo(u.x); a[1] += bfhi(u.x);
            a[2] += bflo(u.y); a[3] += bfhi(u.y);
            a[4] += bflo(u.z); a[5] += bfhi(u.z);
            a[6] += bflo(u.w); a[7] += bfhi(u.w);
        }
        if (l == 0) {  // self (xs already has dinv[d])
            uint4 u = xs4[node];
            a[0] += bflo(u.x); a[1] += bfhi(u.x);
            a[2] += bflo(u.y); a[3] += bfhi(u.y);
            a[4] += bflo(u.z); a[5] += bfhi(u.z);
            a[6] += bflo(u.w); a[7] += bfhi(u.w);
        }
    }
    // butterfly reduce across the 4 edge slots (all lanes get the total)
#pragma unroll
    for (int k = 0; k < 8; k++) {
        a[k] += __shfl_xor(a[k], 1);
        a[k] += __shfl_xor(a[k], 2);
    }
    axl[g * 8 + 2 * l] = di * a[2 * l];      // lane writes channels 2l, 2l+1
    axl[g * 8 + 2 * l + 1] = di * a[2 * l + 1];
    if (l == 0) sdi[g] = di;
    __syncthreads();
    // ---- phase B: GEMM + fp8 store (wave handles 16 nodes) ----
    int wv = tid >> 6, lane = tid & 63;
    int nb = blockIdx.x * 64;
    for (int it = 0; it < 16; it++) {
        int nl = wv * 16 + it;
        int nd = nb + nl;
        if (nd >= n) break;  // wave-uniform
        float h = w[512 + lane];
#pragma unroll
        for (int k = 0; k < 8; k++) h = fmaf(axl[nl * 8 + k], w[k * 64 + lane], h);
        float h1s = fmaxf(h, 0.f) * sdi[nl];
        unsigned word = ((unsigned)__builtin_amdgcn_cvt_pk_fp8_f32(h1s, h1s, 0, false)
                         & 0xFFu) << ((lane & 3) * 8);
        word |= __shfl_xor((int)word, 1);
        word |= __shfl_xor((int)word, 2);
        if ((lane & 3) == 0) h1q[nd * 16 + (lane >> 2)] = word;
    }
}

// ah[d] = dinv[d]*(sum h1s[src] + h1s[d]); fp8 rows (64B = 1 line/edge).
// r23/r29 single-pass: node per QUARTER-WAVE, lane = (edge-slot es, row-
// quarter qp): 16B load per edge, 2-deep; slot partials merged by
// shfl_xor(4,8); es==0 lanes pack+store 32B each of the bf16x2 output row.
// IDEMPOTENT (pure function of inputs) -- r33 probe launches it 6x.
__global__ void agg64(const unsigned int* __restrict__ h1q, const float* __restrict__ dinv,
                      const int* __restrict__ row_start, const int* __restrict__ cnt,
                      const int* __restrict__ csr_src, uint2* __restrict__ ahb, int n) {
    int gid = blockIdx.x * blockDim.x + threadIdx.x;
    int node = gid >> 4;
    if (node >= n) return;
    int cq = threadIdx.x & 15;
    int es = cq >> 2, qp = cq & 3;
    const uint4* h4 = (const uint4*)h1q;  // h1q row = 4 x uint4
    float a[16] = {};
    int e0 = row_start[node], e1 = e0 + cnt[node];
    int e = e0 + es;
    for (; e + 4 < e1; e += 8) {  // 2-deep: 2 x 16B rows in flight per lane
        int sA = csr_src[e], sB = csr_src[e + 4];
        uint4 uA = h4[sA * 4 + qp], uB = h4[sB * 4 + qp];
#pragma unroll
        for (int wdx = 0; wdx < 4; wdx++) {
            unsigned wa = (&uA.x)[wdx], wb = (&uB.x)[wdx];
            v2f la = __builtin_amdgcn_cvt_pk_f32_fp8((int)wa, false);
            v2f ha = __builtin_amdgcn_cvt_pk_f32_fp8((int)wa, true);
            v2f lb = __builtin_amdgcn_cvt_pk_f32_fp8((int)wb, false);
            v2f hb = __builtin_amdgcn_cvt_pk_f32_fp8((int)wb, true);
            a[wdx * 4 + 0] += la[0] + lb[0];
            a[wdx * 4 + 1] += la[1] + lb[1];
            a[wdx * 4 + 2] += ha[0] + hb[0];
            a[wdx * 4 + 3] += ha[1] + hb[1];
        }
    }
    for (; e < e1; e += 4) {
        uint4 u = h4[csr_src[e] * 4 + qp];
#pragma unroll
        for (int wdx = 0; wdx < 4; wdx++) {
            unsigned wu = (&u.x)[wdx];
            v2f lo = __builtin_amdgcn_cvt_pk_f32_fp8((int)wu, false);
            v2f hi = __builtin_amdgcn_cvt_pk_f32_fp8((int)wu, true);
            a[wdx * 4 + 0] += lo[0];
            a[wdx * 4 + 1] += lo[1];
            a[wdx * 4 + 2] += hi[0];
            a[wdx * 4 + 3] += hi[1];
        }
    }
    if (es == 0) {  // self
        uint4 u = h4[node * 4 + qp];
#pragma unroll
        for (int wdx = 0; wdx < 4; wdx++) {
            unsigned wu = (&u.x)[wdx];
            v2f lo = __builtin_amdgcn_cvt_pk_f32_fp8((int)wu, false);
            v2f hi = __builtin_amdgcn_cvt_pk_f32_fp8((int)wu, true);
            a[wdx * 4 + 0] += lo[0];
            a[wdx * 4 + 1] += lo[1];
            a[wdx * 4 + 2] += hi[0];
            a[wdx * 4 + 3] += hi[1];
        }
    }
    // reduce across the 4 edge slots (lanes cq, cq^4, cq^8 share qp)
#pragma unroll
    for (int k = 0; k < 16; k++) {
        a[k] += __shfl_xor(a[k], 4);
        a[k] += __shfl_xor(a[k], 8);
    }
    if (es == 0) {
        float di = dinv[node];
        uint4 r0, r1;
        r0.x = pkbf(di * a[0], di * a[1]);
        r0.y = pkbf(di * a[2], di * a[3]);
        r0.z = pkbf(di * a[4], di * a[5]);
        r0.w = pkbf(di * a[6], di * a[7]);
        r1.x = pkbf(di * a[8], di * a[9]);
        r1.y = pkbf(di * a[10], di * a[11]);
        r1.z = pkbf(di * a[12], di * a[13]);
        r1.w = pkbf(di * a[14], di * a[15]);
        uint4* out4 = (uint4*)ahb;  // 128B row = 8 x uint4
        out4[node * 8 + qp * 2] = r0;      // channels 16qp .. 16qp+7
        out4[node * 8 + qp * 2 + 1] = r1;  // channels 16qp+8 .. 16qp+15
    }
}

// h2 = relu(ah @ W2 + b2) fused with column-sum readout -- on MATRIX CORES.
// r27 structure (A coalesced-through-LDS, slot-XOR swizzle; B-fragments in
// 16 VGPRs). r31a: Wfc applied in-kernel + block reduce -> partial is ONE
// float per block (finish reads 4KB, not 533KB).
// C/D layout (HW-verified): col=lane&31, row=(reg&3)+8*(reg>>2)+4*l5.
__global__ __launch_bounds__(256) void gemm2_fused(
    const uint2* __restrict__ ahb, const float* __restrict__ W2,
    const float* __restrict__ b2, const float* __restrict__ Wfc,
    float* __restrict__ partial, int n) {
    __shared__ __align__(16) uint4 wb4[4 * 4 * 64];  // 16KB B-fragments [w][t][lane]
    __shared__ __align__(16) uint4 atp4[32 * 8];     // 4KB A tile, slot-XOR swizzled
    __shared__ float wsum[4];
    int tid = threadIdx.x;
    // stage W2 -> bf16 B-fragments; j-contiguous over threads => coalesced reads.
    // B[k][j]: lane = 32*(k_rel/8) + (j&31), element = k_rel%8 (dword d = elems 2d,2d+1)
    unsigned* wbd = (unsigned*)wb4;
    for (int i = tid; i < 4096; i += 256) {
        int j = i & 127;
        int r = i >> 7;                 // (t, l5, d)
        int t = r >> 3, l5s = (r >> 2) & 1, d = r & 3;
        int k0 = 16 * t + 8 * l5s + 2 * d;
        unsigned val = pkbf(W2[k0 * 128 + j], W2[(k0 + 1) * 128 + j]);
        int w = j >> 5, lan = l5s * 32 + (j & 31);
        wbd[(((w * 4 + t) * 64) + lan) * 4 + d] = val;
    }
    __syncthreads();
    int lane = tid & 63;
    int w = tid >> 6;          // wave id = column block
    int col = lane & 31;       // A row / B col / C col
    int l5 = lane >> 5;        // K-half (A/B), row-half offset (C)
    // hoist B-fragments to registers; wb4 not read again
    uint4 bf0 = wb4[(w * 4 + 0) * 64 + lane];
    uint4 bf1 = wb4[(w * 4 + 1) * 64 + lane];
    uint4 bf2 = wb4[(w * 4 + 2) * 64 + lane];
    uint4 bf3 = wb4[(w * 4 + 3) * 64 + lane];
    float bj = b2[w * 32 + col];
    const uint4* ahb4 = (const uint4*)ahb;
    float colsum = 0.f;
    int ntiles = (n + 31) >> 5;
    for (int tt = blockIdx.x; tt < ntiles; tt += gridDim.x) {
        int base = tt * 32;
        __syncthreads();  // protects atp4 (previous tile's reads)
        {
            int nl = tid >> 3, s = tid & 7;
            uint4 v = make_uint4(0u, 0u, 0u, 0u);
            if (base + nl < n) v = ahb4[(base + nl) * 8 + s];
            atp4[nl * 8 + (s ^ (nl & 7))] = v;  // swizzle breaks 128B-stride banks
        }
        __syncthreads();
        f32x16 acc = {};
        {
            uint4 a0 = atp4[col * 8 + ((2 * 0 + l5) ^ (col & 7))];
            acc = __builtin_amdgcn_mfma_f32_32x32x16_bf16(asbf8(a0), asbf8(bf0), acc, 0, 0, 0);
            uint4 a1 = atp4[col * 8 + ((2 * 1 + l5) ^ (col & 7))];
            acc = __builtin_amdgcn_mfma_f32_32x32x16_bf16(asbf8(a1), asbf8(bf1), acc, 0, 0, 0);
            uint4 a2 = atp4[col * 8 + ((2 * 2 + l5) ^ (col & 7))];
            acc = __builtin_amdgcn_mfma_f32_32x32x16_bf16(asbf8(a2), asbf8(bf2), acc, 0, 0, 0);
            uint4 a3 = atp4[col * 8 + ((2 * 3 + l5) ^ (col & 7))];
            acc = __builtin_amdgcn_mfma_f32_32x32x16_bf16(asbf8(a3), asbf8(bf3), acc, 0, 0, 0);
        }
        int nvalid = n - base;
        if (nvalid >= 32) {
#pragma unroll
            for (int reg = 0; reg < 16; reg++) colsum += fmaxf(acc[reg] + bj, 0.f);
        } else {
#pragma unroll
            for (int reg = 0; reg < 16; reg++) {
                int rrow = (reg & 3) + 8 * (reg >> 2) + 4 * l5;
                if (rrow < nvalid) colsum += fmaxf(acc[reg] + bj, 0.f);
            }
        }
    }
    colsum += __shfl_xor(colsum, 32);  // merge complementary row halves
    // r31a: apply Wfc and reduce to ONE float per block
    float v = (l5 == 0) ? colsum * Wfc[w * 32 + col] : 0.f;
#pragma unroll
    for (int off = 1; off < 64; off <<= 1) v += __shfl_xor(v, off);
    if (lane == 0) wsum[w] = v;
    __syncthreads();
    if (tid == 0) partial[blockIdx.x] = wsum[0] + wsum[1] + wsum[2] + wsum[3];
}

// out = (sum_b partial[b]) / n + bfc.  (partial already has Wfc applied.)
__global__ __launch_bounds__(256) void finish_kernel(
    const float* __restrict__ partial, const float* __restrict__ bfc,
    float* __restrict__ out, float invN, int G) {
    __shared__ float sh[4];
    int tid = threadIdx.x;
    float s = 0.f;
    for (int b = tid; b < G; b += 256) s += partial[b];
#pragma unroll
    for (int off = 32; off > 0; off >>= 1) s += __shfl_down(s, off);
    if ((tid & 63) == 0) sh[tid >> 6] = s;
    __syncthreads();
    if (tid == 0) out[0] = (sh[0] + sh[1] + sh[2] + sh[3]) * invN + bfc[0];
}

extern "C" void kernel_launch(void* const* d_in, const int* in_sizes, int n_in,
                              void* d_out, int out_size, void* d_ws, size_t ws_size,
                              hipStream_t stream) {
    const float* x   = (const float*)d_in[0];
    const int* ei    = (const int*)d_in[1];
    const float* W1  = (const float*)d_in[2];
    const float* b1  = (const float*)d_in[3];
    const float* W2  = (const float*)d_in[4];
    const float* b2  = (const float*)d_in[5];
    const float* Wfc = (const float*)d_in[6];
    const float* bfc = (const float*)d_in[7];
    float* out = (float*)d_out;

    const int n = in_sizes[0] / 8;
    const int E = in_sizes[1] / 2;

    const int nA = (E + CHUNK - 1) / CHUNK;
    const int B = (n + 255) >> NB_SHIFT;  // buckets of 256 nodes

    char* ws = (char*)d_ws;
    size_t off = 0;
    auto alloc = [&](size_t bytes) -> char* {
        char* p = ws + off;
        off = (off + bytes + 255) & ~(size_t)255;
        return p;
    };
    int*            cursor    = (int*)alloc(512 * 4);
    unsigned int*   bucketed  = (unsigned int*)alloc((size_t)B * BCAP * 4);
    int*            row_start = (int*)alloc((size_t)n * 4);
    int*            cnt       = (int*)alloc((size_t)n * 4);
    float*          dinv      = (float*)alloc((size_t)n * 4);
    int*            csr_src   = (int*)alloc((size_t)B * BCAP * 4);
    unsigned int*   xsb       = (unsigned int*)alloc((size_t)n * 16);  // bf16 rows
    unsigned int*   h1q       = (unsigned int*)alloc((size_t)n * 64);  // fp8 rows
    uint2*          ahb       = (uint2*)alloc((size_t)n * 128);        // bf16 rows
    float*          partial   = (float*)alloc((size_t)G2_GRID * 4);
    (void)ws_size;

    hipMemsetAsync(cursor, 0, 512 * 4, stream);
    scatterA<<<nA, 512, 0, stream>>>(ei, E, cursor, bucketed);
    buildB<<<B, 512, 0, stream>>>(bucketed, cursor, row_start, cnt, dinv, csr_src,
                                  x, xsb, n);
    aggX_gemm1<<<(n + 63) / 64, 256, 0, stream>>>(xsb, dinv, row_start, cnt, csr_src,
                                                  W1, b1, h1q, n);
    // r33 ATTRIBUTION PROBE: 6x idempotent agg64. dTotal = 5*(agg64+gap).
    for (int rep = 0; rep < 6; rep++)
        agg64<<<(n * 16 + 255) / 256, 256, 0, stream>>>(h1q, dinv, row_start, cnt,
                                                        csr_src, ahb, n);
    gemm2_fused<<<G2_GRID, 256, 0, stream>>>(ahb, W2, b2, Wfc, partial, n);
    finish_kernel<<<1, 256, 0, stream>>>(partial, bfc, out, 1.0f / (float)n, G2_GRID);
}

// Round 18
// 227.317 us; speedup vs baseline: 1.2282x; 1.2282x over previous
//
#include <hip/hip_runtime.h>

// ---------------------------------------------------------------------------
// StressGNN: 2-layer GCN, 100k nodes / 1.6M edges, fp32.
//   *** r34 = ATTRIBUTION PROBE #3 (final) ***: pipeline identical to r32
//   (156.3us), but buildB and aggX (both idempotent) launched 4x each.
//   dTotal = 3*(buildB+aggX) + 6*gap. With agg64=23 (r33), gemm2=14,
//   finish=1, memset=2, gaps~10: scatterA = 106 - (buildB+aggX).
//   Probe reverted next round; decision rule in round notes.
//   ---
//   (Â X) W = Â (X W): aggregate in the small dim (8, then 64).
//   norm factored out; h1s fp8 e4m3 rows (64B); xs bf16 (16B, L2-resident);
//   ah bf16x2 (r17). CSR: fixed-capacity buckets (r15).
//   r18 LESSON: edge-parallel scattered 4B stores -> 17x cross-XCD write amp.
//   r19 LESSON: 1.6M device-scope atomicAdds cost ~30-100us.
//   r21 LESSON: scatterA NOT grid/cursor-atomic-bound.
//   r22 WIN (205->196): buildB LDS-staged segment, 256-node buckets.
//   r23/r24 small wins: wide 16B gathers; LDS sort + coalesced write-out.
//   r25 LESSON (286us!): device-scope __threadfence per block serializes the
//     memory system. Finish stays a separate dispatch.
//   r26 LESSON: packed-bf16 FMA gemm2 is VALU-bound.
//   r27 WIN (198->168): gemm2 on v_mfma_f32_32x32x16_bf16.
//   r28 LESSON: direct-global A-fragments uncoalesced; A stays through-LDS.
//   r29 WIN (168->162.7): scatterA/buildB at 512 threads.
//   r30 PROBE: gap <= 1-2us; finish ~6 -> fixed in r32 (~1us).
//   r31 LESSON: two-pass agg64 +18us (shared footprint, no XCD partition).
//   r32 WIN (162.7->156.3): gemm2 applies Wfc + reduces to 1 float/block.
//   r33 PROBE: agg64 ~= 23us, FETCH 68.5MB/dispatch -- near the structural
//     floor for random 64B gathers over a 6.4MB table (> 4MB per-XCD L2;
//     random graph = no locality). agg64 deprioritized (~8us headroom max).
//   r15 lesson: gemm2 grid ~1024; G2_GRID=1042 balances 3125 tiles.
//   r13 lesson: do NOT fuse the gather into the GEMM kernel (occupancy).
//   Assumes n <= 131072 (src fits 17 bits, dst_local fits 8 bits, <=512 bkts).
// ---------------------------------------------------------------------------

#define CHUNK 4096
#define NB_SHIFT 8   // 256 nodes per bucket
#define BCAP 5120    // mean 4096, sigma~64 -> 16-sigma margin
#define G2_GRID 1042

typedef float v2f __attribute__((ext_vector_type(2)));
typedef __bf16 bf16x8 __attribute__((ext_vector_type(8)));
typedef float f32x16 __attribute__((ext_vector_type(16)));

__device__ __forceinline__ unsigned short f2bf(float f) {
    unsigned u = __float_as_uint(f);
    return (unsigned short)((u + 0x7fffu + ((u >> 16) & 1u)) >> 16);
}
__device__ __forceinline__ unsigned pkbf(float a, float b) {
    return ((unsigned)f2bf(b) << 16) | f2bf(a);
}
__device__ __forceinline__ float bflo(unsigned u) { return __uint_as_float(u << 16); }
__device__ __forceinline__ float bfhi(unsigned u) { return __uint_as_float(u & 0xffff0000u); }
__device__ __forceinline__ bf16x8 asbf8(uint4 v) { return __builtin_bit_cast(bf16x8, v); }

// r24 sort + r25b pk-in-LDS + r29: 512 threads (halved phase trip counts).
__global__ __launch_bounds__(512) void scatterA(const int* __restrict__ ei, int E,
                                                int* __restrict__ cursor,
                                                unsigned int* __restrict__ bucketed) {
    __shared__ unsigned int pk[CHUNK];     // 16KB packed edges (chunk order)
    __shared__ unsigned short bk[CHUNK];   // 8KB  bucket id per edge
    __shared__ unsigned int spk[CHUNK];    // 16KB bucket-sorted packed edges
    __shared__ unsigned short sbk[CHUNK];  // 8KB  bucket id per sorted slot
    __shared__ int h[512], hsc[512], lcur[512], rbase[512];  // 8KB
    int tid = threadIdx.x;
    h[tid] = 0;
    lcur[tid] = 0;
    __syncthreads();
    int cbase = blockIdx.x * CHUNK;
    int cN = min(CHUNK, E - cbase);
    const int* src = ei;
    const int* dst = ei + E;
    // phase 1: read edges once; pack into LDS; histogram buckets
    for (int i = tid; i < cN; i += 512) {
        int s = src[cbase + i], d = dst[cbase + i];
        int b = d >> NB_SHIFT;
        pk[i] = (unsigned)s | ((unsigned)(d & 255) << 17);
        bk[i] = (unsigned short)b;
        atomicAdd(&h[b], 1);
    }
    __syncthreads();
    // inclusive Hillis-Steele scan over 512 (one element per thread)
    hsc[tid] = h[tid];
    __syncthreads();
    for (int off = 1; off < 512; off <<= 1) {
        int v0 = (tid >= off) ? hsc[tid - off] : 0;
        __syncthreads();
        hsc[tid] += v0;
        __syncthreads();
    }
    hsc[tid] -= h[tid];  // exclusive (own slot only)
    // global reservation per touched bucket
    if (h[tid]) rbase[tid] = tid * BCAP + atomicAdd(&cursor[tid], h[tid]);
    __syncthreads();
    // phase 2: LDS -> LDS bucket sort
    for (int i = tid; i < cN; i += 512) {
        int b = bk[i];
        int pos = hsc[b] + atomicAdd(&lcur[b], 1);
        spk[pos] = pk[i];
        sbk[pos] = (unsigned short)b;
    }
    __syncthreads();
    // phase 3: coalesced write-out (consecutive lanes -> consecutive addrs)
    for (int p = tid; p < cN; p += 512) {
        int b = sbk[p];
        bucketed[rbase[b] + (p - hsc[b])] = spk[p];
    }
}

// Pass B: one block per 256-node bucket, 512 threads (r29). Segment staged
// in LDS; scan; per-node scatter to LDS scsr (r24); csr_src written
// coalesced. Also writes dinv and the bf16 pre-scaled xsb rows.
// IDEMPOTENT (pure function of bucketed/cursor/x) -- r34 probe runs 4x.
__global__ __launch_bounds__(512) void buildB(
    const unsigned int* __restrict__ bucketed, const int* __restrict__ cursor,
    int* __restrict__ row_start, int* __restrict__ cntg, float* __restrict__ dinv,
    int* __restrict__ csr_src, const float* __restrict__ x,
    unsigned int* __restrict__ xsb, int n) {
    __shared__ unsigned int spk[BCAP];  // 20KB staged segment
    __shared__ int scsr[BCAP];          // 20KB sorted local csr
    __shared__ int cnt[256], sc[256], cur[256];
    __shared__ float sdinv[256];
    int tid = threadIdx.x;
    int b = blockIdx.x;
    int s0 = b * BCAP;
    int m = cursor[b];
    if (tid < 256) cnt[tid] = 0;
    __syncthreads();
    for (int e = tid; e < m; e += 512) {
        unsigned v = bucketed[s0 + e];
        spk[e] = v;
        atomicAdd(&cnt[v >> 17], 1);
    }
    __syncthreads();
    if (tid < 256) sc[tid] = cnt[tid];
    __syncthreads();
    for (int off = 1; off < 256; off <<= 1) {  // inclusive Hillis-Steele over 256
        int v0 = (tid < 256 && tid >= off) ? sc[tid - off] : 0;
        __syncthreads();
        if (tid < 256) sc[tid] += v0;
        __syncthreads();
    }
    int nb0 = b << NB_SHIFT;
    if (tid < 256) {
        int node = nb0 + tid;
        int ex = sc[tid] - cnt[tid];  // exclusive (segment-local)
        cur[tid] = ex;
        float dv = rsqrtf((float)cnt[tid] + 1.0f);
        sdinv[tid] = dv;
        if (node < n) {
            row_start[node] = s0 + ex;
            cntg[node] = cnt[tid];
            dinv[node] = dv;
        }
    }
    __syncthreads();
    // per-node sort into LDS (banked, cheap), then coalesced global write
    for (int e = tid; e < m; e += 512) {
        unsigned v = spk[e];
        int r = atomicAdd(&cur[v >> 17], 1);
        scsr[r] = (int)(v & 0x1FFFFu);
    }
    __syncthreads();
    for (int e = tid; e < m; e += 512) csr_src[s0 + e] = scsr[e];
    // xsb for this bucket's nodes: xsb[(nb0+(i>>2))*4 + (i&3)] == xsb[nb0*4+i]
    int lim = min(n - nb0, 256) * 4;
    for (int i = tid; i < lim; i += 512) {
        float2 v = ((const float2*)x)[nb0 * 4 + i];
        float dvv = sdinv[i >> 2];
        xsb[nb0 * 4 + i] = pkbf(v.x * dvv, v.y * dvv);
    }
}

// fused: ax = dinv[d]*(sum xs[src] + xs[d]);  h1q = fp8(dinv[d]*relu(ax@W1+b1)).
// Phase A (r23): node per 4-LANE GROUP; each lane = one edge SLOT loading the
// full 16B xs row (uint4), 2-deep; slot partials merged by shfl_xor butterfly.
// Phase B: per-wave 8->64 GEMM from LDS ax (broadcast reads) + fp8 store.
// IDEMPOTENT (pure function of inputs) -- r34 probe runs 4x.
__global__ __launch_bounds__(256) void aggX_gemm1(
    const unsigned int* __restrict__ xsb, const float* __restrict__ dinv,
    const int* __restrict__ row_start, const int* __restrict__ cnt,
    const int* __restrict__ csr_src, const float* __restrict__ W1,
    const float* __restrict__ b1, unsigned int* __restrict__ h1q, int n) {
    __shared__ float w[512 + 64];
    __shared__ float axl[64 * 8];  // ax for this block's 64 nodes
    __shared__ float sdi[64];
    int tid = threadIdx.x;
    for (int i = tid; i < 512; i += 256) w[i] = W1[i];
    if (tid < 64) w[512 + tid] = b1[tid];
    // ---- phase A: wide gather ----
    int g = tid >> 2, l = tid & 3;
    int node = blockIdx.x * 64 + g;
    float a[8] = {};
    float di = 0.f;
    if (node < n) {
        di = dinv[node];
        const uint4* xs4 = (const uint4*)xsb;
        int e0 = row_start[node], e1 = e0 + cnt[node];
        int e = e0 + l;
        for (; e + 4 < e1; e += 8) {  // 2-deep: 2 x 16B rows in flight per lane
            int sA = csr_src[e], sB = csr_src[e + 4];
            uint4 uA = xs4[sA], uB = xs4[sB];
            a[0] += bflo(uA.x) + bflo(uB.x);
            a[1] += bfhi(uA.x) + bfhi(uB.x);
            a[2] += bflo(uA.y) + bflo(uB.y);
            a[3] += bfhi(uA.y) + bfhi(uB.y);
            a[4] += bflo(uA.z) + bflo(uB.z);
            a[5] += bfhi(uA.z) + bfhi(uB.z);
            a[6] += bflo(uA.w) + bflo(uB.w);
            a[7] += bfhi(uA.w) + bfhi(uB.w);
        }
        for (; e < e1; e += 4) {
            uint4 u = xs4[csr_src[e]];
            a[0] += bflo(u.x); a[1] += bfhi(u.x);
            a[2] += bflo(u.y); a[3] += bfhi(u.y);
            a[4] += bflo(u.z); a[5] += bfhi(u.z);
            a[6] += bflo(u.w); a[7] += bfhi(u.w);
        }
        if (l == 0) {  // self (xs already has dinv[d])
            uint4 u = xs4[node];
            a[0] += bflo(u.x); a[1] += bfhi(u.x);
            a[2] += bflo(u.y); a[3] += bfhi(u.y);
            a[4] += bflo(u.z); a[5] += bfhi(u.z);
            a[6] += bflo(u.w); a[7] += bfhi(u.w);
        }
    }
    // butterfly reduce across the 4 edge slots (all lanes get the total)
#pragma unroll
    for (int k = 0; k < 8; k++) {
        a[k] += __shfl_xor(a[k], 1);
        a[k] += __shfl_xor(a[k], 2);
    }
    axl[g * 8 + 2 * l] = di * a[2 * l];      // lane writes channels 2l, 2l+1
    axl[g * 8 + 2 * l + 1] = di * a[2 * l + 1];
    if (l == 0) sdi[g] = di;
    __syncthreads();
    // ---- phase B: GEMM + fp8 store (wave handles 16 nodes) ----
    int wv = tid >> 6, lane = tid & 63;
    int nb = blockIdx.x * 64;
    for (int it = 0; it < 16; it++) {
        int nl = wv * 16 + it;
        int nd = nb + nl;
        if (nd >= n) break;  // wave-uniform
        float h = w[512 + lane];
#pragma unroll
        for (int k = 0; k < 8; k++) h = fmaf(axl[nl * 8 + k], w[k * 64 + lane], h);
        float h1s = fmaxf(h, 0.f) * sdi[nl];
        unsigned word = ((unsigned)__builtin_amdgcn_cvt_pk_fp8_f32(h1s, h1s, 0, false)
                         & 0xFFu) << ((lane & 3) * 8);
        word |= __shfl_xor((int)word, 1);
        word |= __shfl_xor((int)word, 2);
        if ((lane & 3) == 0) h1q[nd * 16 + (lane >> 2)] = word;
    }
}

// ah[d] = dinv[d]*(sum h1s[src] + h1s[d]); fp8 rows (64B = 1 line/edge).
// r23/r29 single-pass: node per QUARTER-WAVE, lane = (edge-slot es, row-
// quarter qp): 16B load per edge, 2-deep; slot partials merged by
// shfl_xor(4,8); es==0 lanes pack+store 32B each of the bf16x2 output row.
__global__ void agg64(const unsigned int* __restrict__ h1q, const float* __restrict__ dinv,
                      const int* __restrict__ row_start, const int* __restrict__ cnt,
                      const int* __restrict__ csr_src, uint2* __restrict__ ahb, int n) {
    int gid = blockIdx.x * blockDim.x + threadIdx.x;
    int node = gid >> 4;
    if (node >= n) return;
    int cq = threadIdx.x & 15;
    int es = cq >> 2, qp = cq & 3;
    const uint4* h4 = (const uint4*)h1q;  // h1q row = 4 x uint4
    float a[16] = {};
    int e0 = row_start[node], e1 = e0 + cnt[node];
    int e = e0 + es;
    for (; e + 4 < e1; e += 8) {  // 2-deep: 2 x 16B rows in flight per lane
        int sA = csr_src[e], sB = csr_src[e + 4];
        uint4 uA = h4[sA * 4 + qp], uB = h4[sB * 4 + qp];
#pragma unroll
        for (int wdx = 0; wdx < 4; wdx++) {
            unsigned wa = (&uA.x)[wdx], wb = (&uB.x)[wdx];
            v2f la = __builtin_amdgcn_cvt_pk_f32_fp8((int)wa, false);
            v2f ha = __builtin_amdgcn_cvt_pk_f32_fp8((int)wa, true);
            v2f lb = __builtin_amdgcn_cvt_pk_f32_fp8((int)wb, false);
            v2f hb = __builtin_amdgcn_cvt_pk_f32_fp8((int)wb, true);
            a[wdx * 4 + 0] += la[0] + lb[0];
            a[wdx * 4 + 1] += la[1] + lb[1];
            a[wdx * 4 + 2] += ha[0] + hb[0];
            a[wdx * 4 + 3] += ha[1] + hb[1];
        }
    }
    for (; e < e1; e += 4) {
        uint4 u = h4[csr_src[e] * 4 + qp];
#pragma unroll
        for (int wdx = 0; wdx < 4; wdx++) {
            unsigned wu = (&u.x)[wdx];
            v2f lo = __builtin_amdgcn_cvt_pk_f32_fp8((int)wu, false);
            v2f hi = __builtin_amdgcn_cvt_pk_f32_fp8((int)wu, true);
            a[wdx * 4 + 0] += lo[0];
            a[wdx * 4 + 1] += lo[1];
            a[wdx * 4 + 2] += hi[0];
            a[wdx * 4 + 3] += hi[1];
        }
    }
    if (es == 0) {  // self
        uint4 u = h4[node * 4 + qp];
#pragma unroll
        for (int wdx = 0; wdx < 4; wdx++) {
            unsigned wu = (&u.x)[wdx];
            v2f lo = __builtin_amdgcn_cvt_pk_f32_fp8((int)wu, false);
            v2f hi = __builtin_amdgcn_cvt_pk_f32_fp8((int)wu, true);
            a[wdx * 4 + 0] += lo[0];
            a[wdx * 4 + 1] += lo[1];
            a[wdx * 4 + 2] += hi[0];
            a[wdx * 4 + 3] += hi[1];
        }
    }
    // reduce across the 4 edge slots (lanes cq, cq^4, cq^8 share qp)
#pragma unroll
    for (int k = 0; k < 16; k++) {
        a[k] += __shfl_xor(a[k], 4);
        a[k] += __shfl_xor(a[k], 8);
    }
    if (es == 0) {
        float di = dinv[node];
        uint4 r0, r1;
        r0.x = pkbf(di * a[0], di * a[1]);
        r0.y = pkbf(di * a[2], di * a[3]);
        r0.z = pkbf(di * a[4], di * a[5]);
        r0.w = pkbf(di * a[6], di * a[7]);
        r1.x = pkbf(di * a[8], di * a[9]);
        r1.y = pkbf(di * a[10], di * a[11]);
        r1.z = pkbf(di * a[12], di * a[13]);
        r1.w = pkbf(di * a[14], di * a[15]);
        uint4* out4 = (uint4*)ahb;  // 128B row = 8 x uint4
        out4[node * 8 + qp * 2] = r0;      // channels 16qp .. 16qp+7
        out4[node * 8 + qp * 2 + 1] = r1;  // channels 16qp+8 .. 16qp+15
    }
}

// h2 = relu(ah @ W2 + b2) fused with column-sum readout -- on MATRIX CORES.
// r27 structure (A coalesced-through-LDS, slot-XOR swizzle; B-fragments in
// 16 VGPRs). r31a: Wfc applied in-kernel + block reduce -> partial is ONE
// float per block (finish reads 4KB, not 533KB).
// C/D layout (HW-verified): col=lane&31, row=(reg&3)+8*(reg>>2)+4*l5.
__global__ __launch_bounds__(256) void gemm2_fused(
    const uint2* __restrict__ ahb, const float* __restrict__ W2,
    const float* __restrict__ b2, const float* __restrict__ Wfc,
    float* __restrict__ partial, int n) {
    __shared__ __align__(16) uint4 wb4[4 * 4 * 64];  // 16KB B-fragments [w][t][lane]
    __shared__ __align__(16) uint4 atp4[32 * 8];     // 4KB A tile, slot-XOR swizzled
    __shared__ float wsum[4];
    int tid = threadIdx.x;
    // stage W2 -> bf16 B-fragments; j-contiguous over threads => coalesced reads.
    // B[k][j]: lane = 32*(k_rel/8) + (j&31), element = k_rel%8 (dword d = elems 2d,2d+1)
    unsigned* wbd = (unsigned*)wb4;
    for (int i = tid; i < 4096; i += 256) {
        int j = i & 127;
        int r = i >> 7;                 // (t, l5, d)
        int t = r >> 3, l5s = (r >> 2) & 1, d = r & 3;
        int k0 = 16 * t + 8 * l5s + 2 * d;
        unsigned val = pkbf(W2[k0 * 128 + j], W2[(k0 + 1) * 128 + j]);
        int w = j >> 5, lan = l5s * 32 + (j & 31);
        wbd[(((w * 4 + t) * 64) + lan) * 4 + d] = val;
    }
    __syncthreads();
    int lane = tid & 63;
    int w = tid >> 6;          // wave id = column block
    int col = lane & 31;       // A row / B col / C col
    int l5 = lane >> 5;        // K-half (A/B), row-half offset (C)
    // hoist B-fragments to registers; wb4 not read again
    uint4 bf0 = wb4[(w * 4 + 0) * 64 + lane];
    uint4 bf1 = wb4[(w * 4 + 1) * 64 + lane];
    uint4 bf2 = wb4[(w * 4 + 2) * 64 + lane];
    uint4 bf3 = wb4[(w * 4 + 3) * 64 + lane];
    float bj = b2[w * 32 + col];
    const uint4* ahb4 = (const uint4*)ahb;
    float colsum = 0.f;
    int ntiles = (n + 31) >> 5;
    for (int tt = blockIdx.x; tt < ntiles; tt += gridDim.x) {
        int base = tt * 32;
        __syncthreads();  // protects atp4 (previous tile's reads)
        {
            int nl = tid >> 3, s = tid & 7;
            uint4 v = make_uint4(0u, 0u, 0u, 0u);
            if (base + nl < n) v = ahb4[(base + nl) * 8 + s];
            atp4[nl * 8 + (s ^ (nl & 7))] = v;  // swizzle breaks 128B-stride banks
        }
        __syncthreads();
        f32x16 acc = {};
        {
            uint4 a0 = atp4[col * 8 + ((2 * 0 + l5) ^ (col & 7))];
            acc = __builtin_amdgcn_mfma_f32_32x32x16_bf16(asbf8(a0), asbf8(bf0), acc, 0, 0, 0);
            uint4 a1 = atp4[col * 8 + ((2 * 1 + l5) ^ (col & 7))];
            acc = __builtin_amdgcn_mfma_f32_32x32x16_bf16(asbf8(a1), asbf8(bf1), acc, 0, 0, 0);
            uint4 a2 = atp4[col * 8 + ((2 * 2 + l5) ^ (col & 7))];
            acc = __builtin_amdgcn_mfma_f32_32x32x16_bf16(asbf8(a2), asbf8(bf2), acc, 0, 0, 0);
            uint4 a3 = atp4[col * 8 + ((2 * 3 + l5) ^ (col & 7))];
            acc = __builtin_amdgcn_mfma_f32_32x32x16_bf16(asbf8(a3), asbf8(bf3), acc, 0, 0, 0);
        }
        int nvalid = n - base;
        if (nvalid >= 32) {
#pragma unroll
            for (int reg = 0; reg < 16; reg++) colsum += fmaxf(acc[reg] + bj, 0.f);
        } else {
#pragma unroll
            for (int reg = 0; reg < 16; reg++) {
                int rrow = (reg & 3) + 8 * (reg >> 2) + 4 * l5;
                if (rrow < nvalid) colsum += fmaxf(acc[reg] + bj, 0.f);
            }
        }
    }
    colsum += __shfl_xor(colsum, 32);  // merge complementary row halves
    // r31a: apply Wfc and reduce to ONE float per block
    float v = (l5 == 0) ? colsum * Wfc[w * 32 + col] : 0.f;
#pragma unroll
    for (int off = 1; off < 64; off <<= 1) v += __shfl_xor(v, off);
    if (lane == 0) wsum[w] = v;
    __syncthreads();
    if (tid == 0) partial[blockIdx.x] = wsum[0] + wsum[1] + wsum[2] + wsum[3];
}

// out = (sum_b partial[b]) / n + bfc.  (partial already has Wfc applied.)
__global__ __launch_bounds__(256) void finish_kernel(
    const float* __restrict__ partial, const float* __restrict__ bfc,
    float* __restrict__ out, float invN, int G) {
    __shared__ float sh[4];
    int tid = threadIdx.x;
    float s = 0.f;
    for (int b = tid; b < G; b += 256) s += partial[b];
#pragma unroll
    for (int off = 32; off > 0; off >>= 1) s += __shfl_down(s, off);
    if ((tid & 63) == 0) sh[tid >> 6] = s;
    __syncthreads();
    if (tid == 0) out[0] = (sh[0] + sh[1] + sh[2] + sh[3]) * invN + bfc[0];
}

extern "C" void kernel_launch(void* const* d_in, const int* in_sizes, int n_in,
                              void* d_out, int out_size, void* d_ws, size_t ws_size,
                              hipStream_t stream) {
    const float* x   = (const float*)d_in[0];
    const int* ei    = (const int*)d_in[1];
    const float* W1  = (const float*)d_in[2];
    const float* b1  = (const float*)d_in[3];
    const float* W2  = (const float*)d_in[4];
    const float* b2  = (const float*)d_in[5];
    const float* Wfc = (const float*)d_in[6];
    const float* bfc = (const float*)d_in[7];
    float* out = (float*)d_out;

    const int n = in_sizes[0] / 8;
    const int E = in_sizes[1] / 2;

    const int nA = (E + CHUNK - 1) / CHUNK;
    const int B = (n + 255) >> NB_SHIFT;  // buckets of 256 nodes

    char* ws = (char*)d_ws;
    size_t off = 0;
    auto alloc = [&](size_t bytes) -> char* {
        char* p = ws + off;
        off = (off + bytes + 255) & ~(size_t)255;
        return p;
    };
    int*            cursor    = (int*)alloc(512 * 4);
    unsigned int*   bucketed  = (unsigned int*)alloc((size_t)B * BCAP * 4);
    int*            row_start = (int*)alloc((size_t)n * 4);
    int*            cnt       = (int*)alloc((size_t)n * 4);
    float*          dinv      = (float*)alloc((size_t)n * 4);
    int*            csr_src   = (int*)alloc((size_t)B * BCAP * 4);
    unsigned int*   xsb       = (unsigned int*)alloc((size_t)n * 16);  // bf16 rows
    unsigned int*   h1q       = (unsigned int*)alloc((size_t)n * 64);  // fp8 rows
    uint2*          ahb       = (uint2*)alloc((size_t)n * 128);        // bf16 rows
    float*          partial   = (float*)alloc((size_t)G2_GRID * 4);
    (void)ws_size;

    hipMemsetAsync(cursor, 0, 512 * 4, stream);
    scatterA<<<nA, 512, 0, stream>>>(ei, E, cursor, bucketed);
    // r34 ATTRIBUTION PROBE: 4x idempotent buildB and aggX.
    for (int rep = 0; rep < 4; rep++)
        buildB<<<B, 512, 0, stream>>>(bucketed, cursor, row_start, cnt, dinv, csr_src,
                                      x, xsb, n);
    for (int rep = 0; rep < 4; rep++)
        aggX_gemm1<<<(n + 63) / 64, 256, 0, stream>>>(xsb, dinv, row_start, cnt,
                                                      csr_src, W1, b1, h1q, n);
    agg64<<<(n * 16 + 255) / 256, 256, 0, stream>>>(h1q, dinv, row_start, cnt, csr_src,
                                                    ahb, n);
    gemm2_fused<<<G2_GRID, 256, 0, stream>>>(ahb, W2, b2, Wfc, partial, n);
    finish_kernel<<<1, 256, 0, stream>>>(partial, bfc, out, 1.0f / (float)n, G2_GRID);
}

// Round 20
// 154.916 us; speedup vs baseline: 1.8022x; 1.4674x over previous
//
#include <hip/hip_runtime.h>

// ---------------------------------------------------------------------------
// StressGNN: 2-layer GCN, 100k nodes / 1.6M edges, fp32.
//   *** r35 resubmit -- r19 bench was an infra failure ("container failed
//   twice"), same as r13; kernel audited clean (no fences/syncs/allocs,
//   bounded loops, LDS 46KB, disjoint workspace). ***
//   (Â X) W = Â (X W): aggregate in the small dim (8, then 64).
//   norm factored out; h1s fp8 e4m3 rows (64B); xs bf16 (16B, L2-resident);
//   ah bf16x2 (r17). CSR: per-bucket segments at b*BCAP (consumers unchanged).
//   r18 LESSON: edge-parallel scattered 4B stores -> 17x cross-XCD write amp.
//   r19 LESSON: 1.6M device-scope atomicAdds cost ~30-100us.
//   r21 LESSON: scatterA NOT grid- or cursor-line-bound.
//   r22 WIN (205->196): buildB LDS-staged segment, 256-node buckets.
//   r23/r24 small wins: wide 16B gathers; LDS sort + coalesced write-out.
//   r25 LESSON (286us!): device-scope fences per block serialize the chip.
//   r26 LESSON: packed-bf16 FMA gemm2 is VALU-bound.
//   r27 WIN (198->168): gemm2 on v_mfma_f32_32x32x16_bf16.
//   r28 LESSON: direct-global A-fragments uncoalesced; A stays through-LDS.
//   r29 WIN (168->162.7): scatterA/buildB at 512 threads.
//   r30/r33/r34 PROBES: gap ~1-1.5us; agg64 ~23us (near random-gather floor,
//     FETCH 68.5MB); buildB+aggX ~21us warm. => scatterA ~70-85us: the whale,
//     and its only never-attacked component is the 200k contended cursor
//     atomics + per-block reservation WAIT (occupancy/coalescing/line-spread
//     all tested neutral).
//   r31 LESSON: shared-footprint splits don't fix L2 thrash (need XCD
//     partitioning). r32 WIN (162.7->156.3): Wfc pre-reduce in gemm2.
//   r35: ATOMIC-FREE CSR BUILD. scatterA block owns output region
//     bucketed[blk*CHUNK..] (no cursor/reservation/memset): LDS bucket-sort,
//     stream out coalesced, write 513-entry offs row. buildB gathers bucket
//     b's 391 fragments (thread-per-fragment, LDS prefix of lengths), then
//     proceeds as before. scatterA now IDEMPOTENT (probeable).
//   r15 lesson: gemm2 grid ~1024; G2_GRID=1042 balances 3125 tiles.
//   r13 lesson: do NOT fuse the gather into the GEMM kernel (occupancy).
//   7 dispatches total (no memset).
//   Assumes n <= 131072 (src 17 bits, dst_local 8 bits, <=512 buckets) and
//   nA <= 512 (E <= 2.1M edges at CHUNK=4096).
// ---------------------------------------------------------------------------

#define CHUNK 4096
#define NB_SHIFT 8   // 256 nodes per bucket
#define BCAP 5120    // bucket mean 4092, sigma~64 -> 16-sigma margin
#define G2_GRID 1042

typedef float v2f __attribute__((ext_vector_type(2)));
typedef __bf16 bf16x8 __attribute__((ext_vector_type(8)));
typedef float f32x16 __attribute__((ext_vector_type(16)));

__device__ __forceinline__ unsigned short f2bf(float f) {
    unsigned u = __float_as_uint(f);
    return (unsigned short)((u + 0x7fffu + ((u >> 16) & 1u)) >> 16);
}
__device__ __forceinline__ unsigned pkbf(float a, float b) {
    return ((unsigned)f2bf(b) << 16) | f2bf(a);
}
__device__ __forceinline__ float bflo(unsigned u) { return __uint_as_float(u << 16); }
__device__ __forceinline__ float bfhi(unsigned u) { return __uint_as_float(u & 0xffff0000u); }
__device__ __forceinline__ bf16x8 asbf8(uint4 v) { return __builtin_bit_cast(bf16x8, v); }

// r35: atomic-free. Block blk sorts its CHUNK by bucket in LDS, streams the
// sorted chunk to its OWN region bucketed[blk*CHUNK..], and writes its
// exclusive per-bucket offsets to offs[blk*513 .. +512] (offs[...+512]=cN).
// No cursor, no global atomics, fully coalesced writes. IDEMPOTENT.
__global__ __launch_bounds__(512) void scatterA(const int* __restrict__ ei, int E,
                                                int* __restrict__ offs,
                                                unsigned int* __restrict__ bucketed) {
    __shared__ unsigned int pk[CHUNK];     // 16KB packed edges (chunk order)
    __shared__ unsigned short bk[CHUNK];   // 8KB  bucket id per edge
    __shared__ unsigned int spk[CHUNK];    // 16KB bucket-sorted packed edges
    __shared__ int h[512], hsc[512], lcur[512];  // 6KB
    int tid = threadIdx.x;
    h[tid] = 0;
    lcur[tid] = 0;
    __syncthreads();
    int cbase = blockIdx.x * CHUNK;
    int cN = min(CHUNK, E - cbase);
    const int* src = ei;
    const int* dst = ei + E;
    // phase 1: read edges once; pack into LDS; histogram buckets
    for (int i = tid; i < cN; i += 512) {
        int s = src[cbase + i], d = dst[cbase + i];
        int b = d >> NB_SHIFT;
        pk[i] = (unsigned)s | ((unsigned)(d & 255) << 17);
        bk[i] = (unsigned short)b;
        atomicAdd(&h[b], 1);
    }
    __syncthreads();
    // inclusive Hillis-Steele scan over 512 (one element per thread)
    hsc[tid] = h[tid];
    __syncthreads();
    for (int off = 1; off < 512; off <<= 1) {
        int v0 = (tid >= off) ? hsc[tid - off] : 0;
        __syncthreads();
        hsc[tid] += v0;
        __syncthreads();
    }
    hsc[tid] -= h[tid];  // exclusive (own slot only)
    // publish offsets (coalesced 2KB row)
    offs[blockIdx.x * 513 + tid] = hsc[tid];
    if (tid == 0) offs[blockIdx.x * 513 + 512] = cN;
    __syncthreads();  // hsc final before cross-thread reads in phase 2
    // phase 2: LDS -> LDS bucket sort
    for (int i = tid; i < cN; i += 512) {
        int b = bk[i];
        int pos = hsc[b] + atomicAdd(&lcur[b], 1);
        spk[pos] = pk[i];
    }
    __syncthreads();
    // phase 3: stream sorted chunk to own region (fully coalesced)
    for (int p = tid; p < cN; p += 512) bucketed[cbase + p] = spk[p];
}

// Pass B: one block per 256-node bucket. r35: gather the bucket's fragments
// from the nA block regions (thread-per-fragment; lengths from offs column;
// LDS prefix over lengths), stage in LDS, then as before: histogram by node,
// scan, per-node sort to scsr, coalesced csr_src write, dinv + xsb rows.
__global__ __launch_bounds__(512) void buildB(
    const unsigned int* __restrict__ bucketed, const int* __restrict__ offs,
    int nA, int* __restrict__ row_start, int* __restrict__ cntg,
    float* __restrict__ dinv, int* __restrict__ csr_src,
    const float* __restrict__ x, unsigned int* __restrict__ xsb, int n) {
    __shared__ unsigned int spk[BCAP];  // 20KB staged segment
    __shared__ int scsr[BCAP];          // 20KB sorted local csr
    __shared__ int fsc[512];            // fragment-length scan
    __shared__ int cnt[256], sc[256], cur[256];
    __shared__ float sdinv[256];
    int tid = threadIdx.x;
    int b = blockIdx.x;
    if (tid < 256) cnt[tid] = 0;
    int o0 = 0, len = 0;
    if (tid < nA) {
        o0 = offs[tid * 513 + b];
        len = offs[tid * 513 + b + 1] - o0;
    }
    fsc[tid] = len;
    __syncthreads();
    for (int off = 1; off < 512; off <<= 1) {  // inclusive scan over 512
        int v0 = (tid >= off) ? fsc[tid - off] : 0;
        __syncthreads();
        fsc[tid] += v0;
        __syncthreads();
    }
    int m = fsc[511];  // bucket total
    // stage: thread tid copies its fragment into spk at its prefix position
    {
        int lb = fsc[tid] - len;
        int gb = tid * CHUNK + o0;
        for (int k = 0; k < len; k++) spk[lb + k] = bucketed[gb + k];
    }
    __syncthreads();
    for (int e = tid; e < m; e += 512) atomicAdd(&cnt[spk[e] >> 17], 1);
    __syncthreads();
    if (tid < 256) sc[tid] = cnt[tid];
    __syncthreads();
    for (int off = 1; off < 256; off <<= 1) {  // inclusive scan over 256
        int v0 = (tid < 256 && tid >= off) ? sc[tid - off] : 0;
        __syncthreads();
        if (tid < 256) sc[tid] += v0;
        __syncthreads();
    }
    int nb0 = b << NB_SHIFT;
    int s0 = b * BCAP;
    if (tid < 256) {
        int node = nb0 + tid;
        int ex = sc[tid] - cnt[tid];  // exclusive (segment-local)
        cur[tid] = ex;
        float dv = rsqrtf((float)cnt[tid] + 1.0f);
        sdinv[tid] = dv;
        if (node < n) {
            row_start[node] = s0 + ex;
            cntg[node] = cnt[tid];
            dinv[node] = dv;
        }
    }
    __syncthreads();
    // per-node sort into LDS, then coalesced global write
    for (int e = tid; e < m; e += 512) {
        unsigned v = spk[e];
        int r = atomicAdd(&cur[v >> 17], 1);
        scsr[r] = (int)(v & 0x1FFFFu);
    }
    __syncthreads();
    for (int e = tid; e < m; e += 512) csr_src[s0 + e] = scsr[e];
    // xsb for this bucket's nodes: xsb[(nb0+(i>>2))*4 + (i&3)] == xsb[nb0*4+i]
    int lim = min(n - nb0, 256) * 4;
    for (int i = tid; i < lim; i += 512) {
        float2 v = ((const float2*)x)[nb0 * 4 + i];
        float dvv = sdinv[i >> 2];
        xsb[nb0 * 4 + i] = pkbf(v.x * dvv, v.y * dvv);
    }
}

// fused: ax = dinv[d]*(sum xs[src] + xs[d]);  h1q = fp8(dinv[d]*relu(ax@W1+b1)).
// Phase A (r23): node per 4-LANE GROUP; each lane = one edge SLOT loading the
// full 16B xs row (uint4), 2-deep; slot partials merged by shfl_xor butterfly.
// Phase B: per-wave 8->64 GEMM from LDS ax (broadcast reads) + fp8 store.
__global__ __launch_bounds__(256) void aggX_gemm1(
    const unsigned int* __restrict__ xsb, const float* __restrict__ dinv,
    const int* __restrict__ row_start, const int* __restrict__ cnt,
    const int* __restrict__ csr_src, const float* __restrict__ W1,
    const float* __restrict__ b1, unsigned int* __restrict__ h1q, int n) {
    __shared__ float w[512 + 64];
    __shared__ float axl[64 * 8];  // ax for this block's 64 nodes
    __shared__ float sdi[64];
    int tid = threadIdx.x;
    for (int i = tid; i < 512; i += 256) w[i] = W1[i];
    if (tid < 64) w[512 + tid] = b1[tid];
    // ---- phase A: wide gather ----
    int g = tid >> 2, l = tid & 3;
    int node = blockIdx.x * 64 + g;
    float a[8] = {};
    float di = 0.f;
    if (node < n) {
        di = dinv[node];
        const uint4* xs4 = (const uint4*)xsb;
        int e0 = row_start[node], e1 = e0 + cnt[node];
        int e = e0 + l;
        for (; e + 4 < e1; e += 8) {  // 2-deep: 2 x 16B rows in flight per lane
            int sA = csr_src[e], sB = csr_src[e + 4];
            uint4 uA = xs4[sA], uB = xs4[sB];
            a[0] += bflo(uA.x) + bflo(uB.x);
            a[1] += bfhi(uA.x) + bfhi(uB.x);
            a[2] += bflo(uA.y) + bflo(uB.y);
            a[3] += bfhi(uA.y) + bfhi(uB.y);
            a[4] += bflo(uA.z) + bflo(uB.z);
            a[5] += bfhi(uA.z) + bfhi(uB.z);
            a[6] += bflo(uA.w) + bflo(uB.w);
            a[7] += bfhi(uA.w) + bfhi(uB.w);
        }
        for (; e < e1; e += 4) {
            uint4 u = xs4[csr_src[e]];
            a[0] += bflo(u.x); a[1] += bfhi(u.x);
            a[2] += bflo(u.y); a[3] += bfhi(u.y);
            a[4] += bflo(u.z); a[5] += bfhi(u.z);
            a[6] += bflo(u.w); a[7] += bfhi(u.w);
        }
        if (l == 0) {  // self (xs already has dinv[d])
            uint4 u = xs4[node];
            a[0] += bflo(u.x); a[1] += bfhi(u.x);
            a[2] += bflo(u.y); a[3] += bfhi(u.y);
            a[4] += bflo(u.z); a[5] += bfhi(u.z);
            a[6] += bflo(u.w); a[7] += bfhi(u.w);
        }
    }
    // butterfly reduce across the 4 edge slots (all lanes get the total)
#pragma unroll
    for (int k = 0; k < 8; k++) {
        a[k] += __shfl_xor(a[k], 1);
        a[k] += __shfl_xor(a[k], 2);
    }
    axl[g * 8 + 2 * l] = di * a[2 * l];      // lane writes channels 2l, 2l+1
    axl[g * 8 + 2 * l + 1] = di * a[2 * l + 1];
    if (l == 0) sdi[g] = di;
    __syncthreads();
    // ---- phase B: GEMM + fp8 store (wave handles 16 nodes) ----
    int wv = tid >> 6, lane = tid & 63;
    int nb = blockIdx.x * 64;
    for (int it = 0; it < 16; it++) {
        int nl = wv * 16 + it;
        int nd = nb + nl;
        if (nd >= n) break;  // wave-uniform
        float h = w[512 + lane];
#pragma unroll
        for (int k = 0; k < 8; k++) h = fmaf(axl[nl * 8 + k], w[k * 64 + lane], h);
        float h1s = fmaxf(h, 0.f) * sdi[nl];
        unsigned word = ((unsigned)__builtin_amdgcn_cvt_pk_fp8_f32(h1s, h1s, 0, false)
                         & 0xFFu) << ((lane & 3) * 8);
        word |= __shfl_xor((int)word, 1);
        word |= __shfl_xor((int)word, 2);
        if ((lane & 3) == 0) h1q[nd * 16 + (lane >> 2)] = word;
    }
}

// ah[d] = dinv[d]*(sum h1s[src] + h1s[d]); fp8 rows (64B = 1 line/edge).
// r23/r29 single-pass: node per QUARTER-WAVE, lane = (edge-slot es, row-
// quarter qp): 16B load per edge, 2-deep; slot partials merged by
// shfl_xor(4,8); es==0 lanes pack+store 32B each of the bf16x2 output row.
__global__ void agg64(const unsigned int* __restrict__ h1q, const float* __restrict__ dinv,
                      const int* __restrict__ row_start, const int* __restrict__ cnt,
                      const int* __restrict__ csr_src, uint2* __restrict__ ahb, int n) {
    int gid = blockIdx.x * blockDim.x + threadIdx.x;
    int node = gid >> 4;
    if (node >= n) return;
    int cq = threadIdx.x & 15;
    int es = cq >> 2, qp = cq & 3;
    const uint4* h4 = (const uint4*)h1q;  // h1q row = 4 x uint4
    float a[16] = {};
    int e0 = row_start[node], e1 = e0 + cnt[node];
    int e = e0 + es;
    for (; e + 4 < e1; e += 8) {  // 2-deep: 2 x 16B rows in flight per lane
        int sA = csr_src[e], sB = csr_src[e + 4];
        uint4 uA = h4[sA * 4 + qp], uB = h4[sB * 4 + qp];
#pragma unroll
        for (int wdx = 0; wdx < 4; wdx++) {
            unsigned wa = (&uA.x)[wdx], wb = (&uB.x)[wdx];
            v2f la = __builtin_amdgcn_cvt_pk_f32_fp8((int)wa, false);
            v2f ha = __builtin_amdgcn_cvt_pk_f32_fp8((int)wa, true);
            v2f lb = __builtin_amdgcn_cvt_pk_f32_fp8((int)wb, false);
            v2f hb = __builtin_amdgcn_cvt_pk_f32_fp8((int)wb, true);
            a[wdx * 4 + 0] += la[0] + lb[0];
            a[wdx * 4 + 1] += la[1] + lb[1];
            a[wdx * 4 + 2] += ha[0] + hb[0];
            a[wdx * 4 + 3] += ha[1] + hb[1];
        }
    }
    for (; e < e1; e += 4) {
        uint4 u = h4[csr_src[e] * 4 + qp];
#pragma unroll
        for (int wdx = 0; wdx < 4; wdx++) {
            unsigned wu = (&u.x)[wdx];
            v2f lo = __builtin_amdgcn_cvt_pk_f32_fp8((int)wu, false);
            v2f hi = __builtin_amdgcn_cvt_pk_f32_fp8((int)wu, true);
            a[wdx * 4 + 0] += lo[0];
            a[wdx * 4 + 1] += lo[1];
            a[wdx * 4 + 2] += hi[0];
            a[wdx * 4 + 3] += hi[1];
        }
    }
    if (es == 0) {  // self
        uint4 u = h4[node * 4 + qp];
#pragma unroll
        for (int wdx = 0; wdx < 4; wdx++) {
            unsigned wu = (&u.x)[wdx];
            v2f lo = __builtin_amdgcn_cvt_pk_f32_fp8((int)wu, false);
            v2f hi = __builtin_amdgcn_cvt_pk_f32_fp8((int)wu, true);
            a[wdx * 4 + 0] += lo[0];
            a[wdx * 4 + 1] += lo[1];
            a[wdx * 4 + 2] += hi[0];
            a[wdx * 4 + 3] += hi[1];
        }
    }
    // reduce across the 4 edge slots (lanes cq, cq^4, cq^8 share qp)
#pragma unroll
    for (int k = 0; k < 16; k++) {
        a[k] += __shfl_xor(a[k], 4);
        a[k] += __shfl_xor(a[k], 8);
    }
    if (es == 0) {
        float di = dinv[node];
        uint4 r0, r1;
        r0.x = pkbf(di * a[0], di * a[1]);
        r0.y = pkbf(di * a[2], di * a[3]);
        r0.z = pkbf(di * a[4], di * a[5]);
        r0.w = pkbf(di * a[6], di * a[7]);
        r1.x = pkbf(di * a[8], di * a[9]);
        r1.y = pkbf(di * a[10], di * a[11]);
        r1.z = pkbf(di * a[12], di * a[13]);
        r1.w = pkbf(di * a[14], di * a[15]);
        uint4* out4 = (uint4*)ahb;  // 128B row = 8 x uint4
        out4[node * 8 + qp * 2] = r0;      // channels 16qp .. 16qp+7
        out4[node * 8 + qp * 2 + 1] = r1;  // channels 16qp+8 .. 16qp+15
    }
}

// h2 = relu(ah @ W2 + b2) fused with column-sum readout -- on MATRIX CORES.
// r27 structure (A coalesced-through-LDS, slot-XOR swizzle; B-fragments in
// 16 VGPRs). r31a: Wfc applied in-kernel + block reduce -> partial is ONE
// float per block. C/D layout: col=lane&31, row=(reg&3)+8*(reg>>2)+4*l5.
__global__ __launch_bounds__(256) void gemm2_fused(
    const uint2* __restrict__ ahb, const float* __restrict__ W2,
    const float* __restrict__ b2, const float* __restrict__ Wfc,
    float* __restrict__ partial, int n) {
    __shared__ __align__(16) uint4 wb4[4 * 4 * 64];  // 16KB B-fragments [w][t][lane]
    __shared__ __align__(16) uint4 atp4[32 * 8];     // 4KB A tile, slot-XOR swizzled
    __shared__ float wsum[4];
    int tid = threadIdx.x;
    // stage W2 -> bf16 B-fragments; j-contiguous over threads => coalesced reads.
    unsigned* wbd = (unsigned*)wb4;
    for (int i = tid; i < 4096; i += 256) {
        int j = i & 127;
        int r = i >> 7;                 // (t, l5, d)
        int t = r >> 3, l5s = (r >> 2) & 1, d = r & 3;
        int k0 = 16 * t + 8 * l5s + 2 * d;
        unsigned val = pkbf(W2[k0 * 128 + j], W2[(k0 + 1) * 128 + j]);
        int w = j >> 5, lan = l5s * 32 + (j & 31);
        wbd[(((w * 4 + t) * 64) + lan) * 4 + d] = val;
    }
    __syncthreads();
    int lane = tid & 63;
    int w = tid >> 6;          // wave id = column block
    int col = lane & 31;       // A row / B col / C col
    int l5 = lane >> 5;        // K-half (A/B), row-half offset (C)
    uint4 bf0 = wb4[(w * 4 + 0) * 64 + lane];
    uint4 bf1 = wb4[(w * 4 + 1) * 64 + lane];
    uint4 bf2 = wb4[(w * 4 + 2) * 64 + lane];
    uint4 bf3 = wb4[(w * 4 + 3) * 64 + lane];
    float bj = b2[w * 32 + col];
    const uint4* ahb4 = (const uint4*)ahb;
    float colsum = 0.f;
    int ntiles = (n + 31) >> 5;
    for (int tt = blockIdx.x; tt < ntiles; tt += gridDim.x) {
        int base = tt * 32;
        __syncthreads();  // protects atp4 (previous tile's reads)
        {
            int nl = tid >> 3, s = tid & 7;
            uint4 v = make_uint4(0u, 0u, 0u, 0u);
            if (base + nl < n) v = ahb4[(base + nl) * 8 + s];
            atp4[nl * 8 + (s ^ (nl & 7))] = v;  // swizzle breaks 128B-stride banks
        }
        __syncthreads();
        f32x16 acc = {};
        {
            uint4 a0 = atp4[col * 8 + ((2 * 0 + l5) ^ (col & 7))];
            acc = __builtin_amdgcn_mfma_f32_32x32x16_bf16(asbf8(a0), asbf8(bf0), acc, 0, 0, 0);
            uint4 a1 = atp4[col * 8 + ((2 * 1 + l5) ^ (col & 7))];
            acc = __builtin_amdgcn_mfma_f32_32x32x16_bf16(asbf8(a1), asbf8(bf1), acc, 0, 0, 0);
            uint4 a2 = atp4[col * 8 + ((2 * 2 + l5) ^ (col & 7))];
            acc = __builtin_amdgcn_mfma_f32_32x32x16_bf16(asbf8(a2), asbf8(bf2), acc, 0, 0, 0);
            uint4 a3 = atp4[col * 8 + ((2 * 3 + l5) ^ (col & 7))];
            acc = __builtin_amdgcn_mfma_f32_32x32x16_bf16(asbf8(a3), asbf8(bf3), acc, 0, 0, 0);
        }
        int nvalid = n - base;
        if (nvalid >= 32) {
#pragma unroll
            for (int reg = 0; reg < 16; reg++) colsum += fmaxf(acc[reg] + bj, 0.f);
        } else {
#pragma unroll
            for (int reg = 0; reg < 16; reg++) {
                int rrow = (reg & 3) + 8 * (reg >> 2) + 4 * l5;
                if (rrow < nvalid) colsum += fmaxf(acc[reg] + bj, 0.f);
            }
        }
    }
    colsum += __shfl_xor(colsum, 32);  // merge complementary row halves
    float v = (l5 == 0) ? colsum * Wfc[w * 32 + col] : 0.f;
#pragma unroll
    for (int off = 1; off < 64; off <<= 1) v += __shfl_xor(v, off);
    if (lane == 0) wsum[w] = v;
    __syncthreads();
    if (tid == 0) partial[blockIdx.x] = wsum[0] + wsum[1] + wsum[2] + wsum[3];
}

// out = (sum_b partial[b]) / n + bfc.  (partial already has Wfc applied.)
__global__ __launch_bounds__(256) void finish_kernel(
    const float* __restrict__ partial, const float* __restrict__ bfc,
    float* __restrict__ out, float invN, int G) {
    __shared__ float sh[4];
    int tid = threadIdx.x;
    float s = 0.f;
    for (int b = tid; b < G; b += 256) s += partial[b];
#pragma unroll
    for (int off = 32; off > 0; off >>= 1) s += __shfl_down(s, off);
    if ((tid & 63) == 0) sh[tid >> 6] = s;
    __syncthreads();
    if (tid == 0) out[0] = (sh[0] + sh[1] + sh[2] + sh[3]) * invN + bfc[0];
}

extern "C" void kernel_launch(void* const* d_in, const int* in_sizes, int n_in,
                              void* d_out, int out_size, void* d_ws, size_t ws_size,
                              hipStream_t stream) {
    const float* x   = (const float*)d_in[0];
    const int* ei    = (const int*)d_in[1];
    const float* W1  = (const float*)d_in[2];
    const float* b1  = (const float*)d_in[3];
    const float* W2  = (const float*)d_in[4];
    const float* b2  = (const float*)d_in[5];
    const float* Wfc = (const float*)d_in[6];
    const float* bfc = (const float*)d_in[7];
    float* out = (float*)d_out;

    const int n = in_sizes[0] / 8;
    const int E = in_sizes[1] / 2;

    const int nA = (E + CHUNK - 1) / CHUNK;    // scatter blocks (<= 512)
    const int B = (n + 255) >> NB_SHIFT;       // buckets of 256 nodes

    char* ws = (char*)d_ws;
    size_t off = 0;
    auto alloc = [&](size_t bytes) -> char* {
        char* p = ws + off;
        off = (off + bytes + 255) & ~(size_t)255;
        return p;
    };
    int*            offs      = (int*)alloc((size_t)nA * 513 * 4);      // per-block bucket offsets
    unsigned int*   bucketed  = (unsigned int*)alloc((size_t)nA * CHUNK * 4);
    int*            row_start = (int*)alloc((size_t)n * 4);
    int*            cnt       = (int*)alloc((size_t)n * 4);
    float*          dinv      = (float*)alloc((size_t)n * 4);
    int*            csr_src   = (int*)alloc((size_t)B * BCAP * 4);
    unsigned int*   xsb       = (unsigned int*)alloc((size_t)n * 16);  // bf16 rows
    unsigned int*   h1q       = (unsigned int*)alloc((size_t)n * 64);  // fp8 rows
    uint2*          ahb       = (uint2*)alloc((size_t)n * 128);        // bf16 rows
    float*          partial   = (float*)alloc((size_t)G2_GRID * 4);
    (void)ws_size;

    scatterA<<<nA, 512, 0, stream>>>(ei, E, offs, bucketed);
    buildB<<<B, 512, 0, stream>>>(bucketed, offs, nA, row_start, cnt, dinv, csr_src,
                                  x, xsb, n);
    aggX_gemm1<<<(n + 63) / 64, 256, 0, stream>>>(xsb, dinv, row_start, cnt, csr_src,
                                                  W1, b1, h1q, n);
    agg64<<<(n * 16 + 255) / 256, 256, 0, stream>>>(h1q, dinv, row_start, cnt, csr_src,
                                                    ahb, n);
    gemm2_fused<<<G2_GRID, 256, 0, stream>>>(ahb, W2, b2, Wfc, partial, n);
    finish_kernel<<<1, 256, 0, stream>>>(partial, bfc, out, 1.0f / (float)n, G2_GRID);
}